// Round 1
// baseline (2071.938 us; speedup 1.0000x reference)
//
#include <hip/hip_runtime.h>

#define NR 16384          // N rows
#define NCOL 128          // fused width (ys|yu)

typedef float  floatx4 __attribute__((ext_vector_type(4)));
typedef short  shortx8 __attribute__((ext_vector_type(8)));

__device__ __forceinline__ unsigned short f2bf(float f) {
    unsigned u = __float_as_uint(f);
    u += 0x7FFF + ((u >> 16) & 1);          // round-to-nearest-even
    return (unsigned short)(u >> 16);
}

__device__ __forceinline__ float elu(float x) {
    return x > 0.0f ? x : (__expf(x) - 1.0f);
}

// ---------------------------------------------------------------------------
// k_transform: XT[j][m] = bf16( sum_k in[m][(j>>6)*64+k] * W[k][j&63] )
//   mode nsum==0: in = elu(src[m*rowStride + col])         (layer-0 input z)
//   mode nsum>0 : in = elu( sum_t partial + bias[col&63] ) (mid-layer)
// One block = 64 rows of m. grid = NR/64 = 256.
// ---------------------------------------------------------------------------
__global__ __launch_bounds__(256) void k_transform(
    const float* __restrict__ src, long rowStride, int nsum, long sumStride,
    const float* __restrict__ bias,
    const float* __restrict__ W,
    unsigned short* __restrict__ XT)
{
    __shared__ float ly[64][129];
    const int tid = threadIdx.x;
    const long m0 = (long)blockIdx.x * 64;

    // phase 1: build elu'd input rows in LDS (coalesced on j)
    {
        const int j  = tid & 127;
        const int rh = tid >> 7;            // 0/1
        for (int ri = 0; ri < 32; ++ri) {
            int  rowL = ri * 2 + rh;
            long row  = m0 + rowL;
            float v;
            if (nsum == 0) {
                v = elu(src[row * rowStride + j]);
            } else {
                float s = bias[j & 63];
                for (int t = 0; t < nsum; ++t)
                    s += src[(long)t * sumStride + row * rowStride + j];
                v = elu(s);
            }
            ly[rowL][j] = v;
        }
    }
    __syncthreads();

    // phase 2: multiply by W (64x64) per half, write transposed bf16 (coalesced on m)
    {
        const int m  = tid & 63;
        const int jq = tid >> 6;            // 0..3
        for (int jj = 0; jj < 32; ++jj) {
            int jcol = jj * 4 + jq;
            const float* wcol = W + (jcol & 63);
            const float* yrow = &ly[m][(jcol >> 6) * 64];
            float s = 0.0f;
            #pragma unroll
            for (int k = 0; k < 64; ++k)
                s += yrow[k] * wcol[k * 64];
            XT[(long)jcol * NR + m0 + m] = f2bf(s);
        }
    }
}

// ---------------------------------------------------------------------------
// k_gemm: part[split][m][j] = sum_{k in split} adj[m][k] * X[k][j]
//   X given transposed bf16 (XT[j][k], k-contiguous).
//   No LDS, no barriers: each wave owns 32 rows x 128 cols, streams K.
//   grid = 128 * ksplit blocks of 256 threads (4 waves).
// ---------------------------------------------------------------------------
__global__ __launch_bounds__(256, 2) void k_gemm(
    const float* __restrict__ adj,
    const unsigned short* __restrict__ XT,
    float* __restrict__ part,
    int ksplit)
{
    const int tid  = threadIdx.x;
    const int wave = tid >> 6;
    const int lane = tid & 63;
    const int q    = lane >> 4;             // 0..3
    const int r    = lane & 15;             // 0..15

    const int mblk  = blockIdx.x & 127;
    const int split = blockIdx.x >> 7;

    const int  rowBase = mblk * 128 + wave * 32;
    const int  kLen    = NR / ksplit;
    const long kBase   = (long)split * kLen;
    const int  iters   = kLen >> 5;         // K-steps of 32

    floatx4 acc[2][8] = {};

    const float*          pa0 = adj + (long)(rowBase + r) * NR + kBase + (long)q * 8;
    const float*          pa1 = pa0 + 16L * NR;
    const unsigned short* pb  = XT  + (long)r * NR + kBase + (long)q * 8;

    for (int it = 0; it < iters; ++it) {
        const long ko = (long)it * 32;

        float4 a0lo = *(const float4*)(pa0 + ko);
        float4 a0hi = *(const float4*)(pa0 + ko + 4);
        float4 a1lo = *(const float4*)(pa1 + ko);
        float4 a1hi = *(const float4*)(pa1 + ko + 4);

        shortx8 b[8];
        #pragma unroll
        for (int nt = 0; nt < 8; ++nt)
            b[nt] = *(const shortx8*)(pb + (long)nt * 16 * NR + ko);

        shortx8 a0, a1;
        a0[0] = (short)f2bf(a0lo.x); a0[1] = (short)f2bf(a0lo.y);
        a0[2] = (short)f2bf(a0lo.z); a0[3] = (short)f2bf(a0lo.w);
        a0[4] = (short)f2bf(a0hi.x); a0[5] = (short)f2bf(a0hi.y);
        a0[6] = (short)f2bf(a0hi.z); a0[7] = (short)f2bf(a0hi.w);
        a1[0] = (short)f2bf(a1lo.x); a1[1] = (short)f2bf(a1lo.y);
        a1[2] = (short)f2bf(a1lo.z); a1[3] = (short)f2bf(a1lo.w);
        a1[4] = (short)f2bf(a1hi.x); a1[5] = (short)f2bf(a1hi.y);
        a1[6] = (short)f2bf(a1hi.z); a1[7] = (short)f2bf(a1hi.w);

        #pragma unroll
        for (int nt = 0; nt < 8; ++nt) {
            acc[0][nt] = __builtin_amdgcn_mfma_f32_16x16x32_bf16(a0, b[nt], acc[0][nt], 0, 0, 0);
            acc[1][nt] = __builtin_amdgcn_mfma_f32_16x16x32_bf16(a1, b[nt], acc[1][nt], 0, 0, 0);
        }
    }

    // store fp32 partials; C/D layout: col = lane&15, row = q*4 + reg
    float* po = part + ((long)split * NR + rowBase) * NCOL;
    #pragma unroll
    for (int mt = 0; mt < 2; ++mt) {
        #pragma unroll
        for (int nt = 0; nt < 8; ++nt) {
            #pragma unroll
            for (int g = 0; g < 4; ++g) {
                int rr = mt * 16 + q * 4 + g;
                int cc = nt * 16 + r;
                po[(long)rr * NCOL + cc] = acc[mt][nt][g];
            }
        }
    }
}

// ---------------------------------------------------------------------------
// k_final: y2 = elu(sum partials + b1);  out = y2 @ Wl[0:128] + za @ Wl[128:192] + bl
// One block = 4 rows. grid = NR/4 = 4096.
// ---------------------------------------------------------------------------
__global__ __launch_bounds__(256) void k_final(
    const float* __restrict__ part, int nsum, long sumStride,
    const float* __restrict__ bias,      // bs[1]
    const float* __restrict__ z,         // for za = z[:,128:192]
    const float* __restrict__ Wl,
    const float* __restrict__ bl,
    float* __restrict__ out)
{
    __shared__ float ly[4][129];
    __shared__ float lza[4][65];
    const int tid = threadIdx.x;
    const long m0 = (long)blockIdx.x * 4;

    {
        const int j  = tid & 127;
        const int rh = tid >> 7;
        for (int ri = 0; ri < 2; ++ri) {
            int  rowL = ri * 2 + rh;
            long row  = m0 + rowL;
            float s = bias[j & 63];
            for (int t = 0; t < nsum; ++t)
                s += part[(long)t * sumStride + row * 128 + j];
            ly[rowL][j] = elu(s);
        }
        int rz = tid >> 6;
        int cz = tid & 63;
        lza[rz][cz] = z[(m0 + rz) * 192 + 128 + cz];
    }
    __syncthreads();

    const int rowL = tid >> 6;
    const int c    = tid & 63;
    float s = bl[c];
    const float* yrow = ly[rowL];
    #pragma unroll 8
    for (int k = 0; k < 128; ++k) s += yrow[k] * Wl[k * 64 + c];
    const float* zrow = lza[rowL];
    #pragma unroll 8
    for (int k = 0; k < 64; ++k) s += zrow[k] * Wl[(128 + k) * 64 + c];
    out[(m0 + rowL) * 64 + c] = s;
}

// ---------------------------------------------------------------------------
extern "C" void kernel_launch(void* const* d_in, const int* in_sizes, int n_in,
                              void* d_out, int out_size, void* d_ws, size_t ws_size,
                              hipStream_t stream)
{
    const float* z   = (const float*)d_in[0];   // (16384, 192)
    const float* adj = (const float*)d_in[1];   // (16384, 16384)
    const float* Ws  = (const float*)d_in[2];   // (2, 64, 64)
    const float* bs  = (const float*)d_in[3];   // (2, 64)
    const float* Wl  = (const float*)d_in[4];   // (192, 64)
    const float* bl  = (const float*)d_in[5];   // (64,)
    float* out = (float*)d_out;

    // ws layout: X0T (4 MiB bf16) | X1T (4 MiB bf16) | partials (ksplit * 8 MiB fp32)
    unsigned short* X0T = (unsigned short*)d_ws;
    unsigned short* X1T = X0T + (size_t)NCOL * NR;
    float*          part = (float*)(X1T + (size_t)NCOL * NR);
    size_t fixed = (size_t)2 * NCOL * NR * sizeof(unsigned short);

    int ksplit = 8;
    while (ksplit > 1 &&
           fixed + (size_t)ksplit * NR * NCOL * sizeof(float) > ws_size)
        ksplit >>= 1;

    const long sumStride = (long)NR * NCOL;

    // layer 0 input transform: X0 = elu(z[:, :128]) @ blockdiag(W0, W0)
    k_transform<<<256, 256, 0, stream>>>(z, 192L, 0, 0L, nullptr, Ws, X0T);
    // layer 1 spmm: partials = adj @ X0
    k_gemm<<<128 * ksplit, 256, 0, stream>>>(adj, X0T, part, ksplit);
    // y1 = elu(sum + bs[0]); X1 = y1 @ blockdiag(W1, W1)
    k_transform<<<256, 256, 0, stream>>>(part, 128L, ksplit, sumStride, bs, Ws + 64 * 64, X1T);
    // layer 2 spmm: partials = adj @ X1
    k_gemm<<<128 * ksplit, 256, 0, stream>>>(adj, X1T, part, ksplit);
    // y2 = elu(sum + bs[1]); out = y2 @ Wl[:128] + za @ Wl[128:] + bl
    k_final<<<NR / 4, 256, 0, stream>>>(part, ksplit, sumStride, bs + 64, z, Wl, bl, out);
}